// Round 4
// baseline (1232.617 us; speedup 1.0000x reference)
//
#include <hip/hip_runtime.h>
#include <hip/hip_cooperative_groups.h>
#include <math.h>

namespace cg = cooperative_groups;

#define NN 100000
#define NE 200000
#define HD 128
#define CAPN 4096
#define CAPE 8192
#define NGROUP 21
#define AP 136   // bf16 LDS row pitch
#define NBLK 256
#define NTHR 256
#define TOTTHR (NBLK * NTHR)

typedef short bf16x8 __attribute__((ext_vector_type(8)));
typedef float f32x4 __attribute__((ext_vector_type(4)));

// workspace byte offsets (128B aligned)
#define OFF_NCNT   0          // 21 ints
#define OFF_ECNT   256        // 21 ints
#define OFF_HSTYPE 512        // 6*128 f32
#define OFF_HSW1   3584       // 3*6*128 f32
#define OFF_WBMLP  12800      // 3 gi x 3 layer x 16384 bf16 (swizzled B-frags)
#define OFF_WBIH   307712     // 3 gi x 49152 bf16 (wih^T swizzled B-frags)
#define OFF_NLIST  602624     // 21*4096 ints
#define OFF_NSLOT  946688     // NN ints
#define OFF_ESRC   1346688    // 21*8192 ints
#define OFF_EDSL   2034816    // 21*8192 ints
#define OFF_MSG    2722944    // 3*4096*128 f32  (6291456 B)
#define MSG_BYTES  6291456

__device__ __forceinline__ int gi_of(int g) {
    return (g == 3) ? 0 : (g == 2) ? 1 : (g == 5) ? 2 : -1;
}

__device__ __forceinline__ unsigned short f2bf(float f) {
    unsigned int u = __float_as_uint(f);
    u += 0x7FFF + ((u >> 16) & 1);   // RNE
    return (unsigned short)(u >> 16);
}

struct Params {
    const int *gate, *lvl, *ei;
    const float *Ws, *Wt, *hs_W, *hs_b;
    const float *w1, *b1, *w2, *b2, *w3, *b3;
    const float *wih, *bih, *bhh;
    float* out;
    int* ncnt; int* ecnt;
    float* hs_type; float* hsW1;
    unsigned short* wbmlp; unsigned short* wbih;
    int* nlist; int* nslot; int* esrc; int* edsl;
    float* msg;
};

// ---------------------------------------------------------------------------
// One cooperative kernel: prep + 7 levels of (edge-MLP -> GRU), grid.sync()
// between dependent phases. msg/gru tile bodies are barrier-free (wave-local
// staging; metadata via __shfl).
// ---------------------------------------------------------------------------
__global__ __launch_bounds__(NTHR) void fused_kernel(Params p) {
    cg::grid_group grid = cg::this_grid();

    __shared__ unsigned short A[64 * AP];   // act tile (msg) / msg tile (gru)
    __shared__ float hsw[3 * 6 * 132];      // hsW1 for all gi, padded pitch
    __shared__ float lht[6 * HD];           // precompute scratch (block 0)
    __shared__ int lcnt[NGROUP], lbase[NGROUP];

    const int bid = blockIdx.x, tid = threadIdx.x;
    const int ln = tid & 63, wv = tid >> 6;
    const int lc = ln & 15, quad = ln >> 4;
    const int rbase = wv * 16;
    float* hfout = p.out + (size_t)NN * HD;

    // ===== Phase A: precompute (block 0) + weight swizzle + group_nodes =====
    if (bid == 0) {
        for (int idx = tid; idx < 6 * HD; idx += NTHR) {
            int t = idx >> 7, c = idx & 127;
            float acc = p.hs_b[c];
            for (int k = 0; k < HD; k++) acc = fmaf(p.Ws[t * HD + k], p.hs_W[k * HD + c], acc);
            for (int k = 0; k < HD; k++) acc = fmaf(p.Wt[t * HD + k], p.hs_W[(HD + k) * HD + c], acc);
            lht[idx] = acc;
            p.hs_type[idx] = acc;
        }
        __syncthreads();
        for (int idx = tid; idx < 3 * 6 * HD; idx += NTHR) {
            int gi = idx / (6 * HD);
            int t = (idx >> 7) % 6;
            int c = idx & 127;
            const float* w = p.w1 + gi * (2 * HD * HD);  // top half rows 0..127
            float acc = 0.f;
            for (int k = 0; k < HD; k++) acc = fmaf(lht[t * HD + k], w[k * HD + c], acc);
            p.hsW1[idx] = acc;
        }
    }
    // weight swizzle into MFMA B-fragment layout (all blocks, strided)
    for (int id = bid * NTHR + tid; id < 3 * 3 * 16384 + 3 * 49152; id += TOTTHR) {
        if (id < 3 * 3 * 16384) {
            int gi = id / 49152;
            int rem = id % 49152;
            int layer = rem / 16384;
            int e = rem % 16384;
            int k = e >> 7, n = e & 127;
            float v;
            if (layer == 0)      v = p.w1[gi * (2 * HD * HD) + (HD + k) * HD + n];
            else if (layer == 1) v = p.w2[gi * (HD * HD) + k * HD + n];
            else                 v = p.w3[gi * (HD * HD) + k * HD + n];
            int nt = n >> 4, kc = k >> 5, kq = (k >> 3) & 3, j = k & 7;
            int L = (kq << 4) | (n & 15);
            p.wbmlp[(size_t)(gi * 3 + layer) * 16384 + ((nt * 4 + kc) * 64 + L) * 8 + j] = f2bf(v);
        } else {
            int id2 = id - 3 * 3 * 16384;
            int gi = id2 / 49152;
            int e = id2 % 49152;
            int k = e / 384, n = e % 384;             // B[k][n] = wih[n][k]
            float v = p.wih[gi * (384 * HD) + n * HD + k];
            int nt = n >> 4, kc = k >> 5, kq = (k >> 3) & 3, j = k & 7;
            int L = (kq << 4) | (n & 15);
            p.wbih[(size_t)gi * 49152 + ((nt * 4 + kc) * 64 + L) * 8 + j] = f2bf(v);
        }
    }
    // group_nodes (LDS-aggregated, strided)
    for (int base = 0; base < NN; base += TOTTHR) {
        if (tid < NGROUP) lcnt[tid] = 0;
        __syncthreads();
        int i = base + bid * NTHR + tid;
        int glob = -1, local = 0;
        if (i < NN) {
            int gi = gi_of(p.gate[i]);
            int l = p.lvl[i];
            if (gi >= 0 && l >= 1) {
                glob = (l - 1) * 3 + gi;
                local = atomicAdd(&lcnt[glob], 1);
            }
        }
        __syncthreads();
        if (tid < NGROUP) {
            int c = lcnt[tid];
            lbase[tid] = c ? atomicAdd(&p.ncnt[tid], c) : 0;
        }
        __syncthreads();
        if (glob >= 0) {
            int slot = lbase[glob] + local;
            if (slot < CAPN) {
                p.nlist[glob * CAPN + slot] = i;
                p.nslot[i] = slot;
            }
        }
        __syncthreads();
    }

    grid.sync();

    // ===== Phase B: scatter hs / zero hf + group_edges + stage hsw =====
    {
        const float4* ht4 = (const float4*)p.hs_type;
        float4* o4 = (float4*)p.out;
        for (int idx = bid * NTHR + tid; idx < NN * 32; idx += TOTTHR) {
            int i = idx >> 5, q = idx & 31;
            o4[idx] = ht4[p.gate[i] * 32 + q];
            o4[(size_t)NN * 32 + idx] = make_float4(0.f, 0.f, 0.f, 0.f);
        }
    }
    for (int base = 0; base < NE; base += TOTTHR) {
        if (tid < NGROUP) lcnt[tid] = 0;
        __syncthreads();
        int e = base + bid * NTHR + tid;
        int glob = -1, local = 0, s = 0, dsl = 0;
        if (e < NE) {
            int d = p.ei[NE + e];
            int gi = gi_of(p.gate[d]);
            int l = p.lvl[d];
            if (gi >= 0 && l >= 1) {
                glob = (l - 1) * 3 + gi;
                local = atomicAdd(&lcnt[glob], 1);
                s = p.ei[e];
                dsl = p.nslot[d];
            }
        }
        __syncthreads();
        if (tid < NGROUP) {
            int c = lcnt[tid];
            lbase[tid] = c ? atomicAdd(&p.ecnt[tid], c) : 0;
        }
        __syncthreads();
        if (glob >= 0) {
            int slot = lbase[glob] + local;
            if (slot < CAPE) {
                p.esrc[glob * CAPE + slot] = s;
                p.edsl[glob * CAPE + slot] = dsl;
            }
        }
        __syncthreads();
    }
    // stage hsW1 for all 3 gi into LDS once (reused by every level)
    for (int i = tid; i < 3 * 6 * 132; i += NTHR) {
        int g = i / 792, rem = i % 792, t = rem / 132, c = rem % 132;
        hsw[i] = (c < HD) ? p.hsW1[(g * 6 + t) * HD + c] : 0.f;
    }

    grid.sync();   // includes block barrier -> hsw visible

    // ===== Level loop =====
    for (int l = 1; l < 8; l++) {
        // ---- msg phase: 3-layer edge MLP + atomic scatter into msg ----
        for (int t = bid; t < 384; t += NBLK) {
            int gi = t % 3;
            int tile = (t / 3) * 64;
            int glob = (l - 1) * 3 + gi;
            int cnt = p.ecnt[glob]; if (cnt > CAPE) cnt = CAPE;
            if (tile >= cnt) continue;
            int nv = min(64, cnt - tile);

            const int* es = p.esrc + glob * CAPE + tile;
            const int* ed = p.edsl + glob * CAPE + tile;

            // wave-local staging of hf[src] (bf16) into A rows rbase..rbase+15
            {
                int row = rbase + (ln >> 2), q = ln & 3;
                unsigned int* Au = (unsigned int*)A;
                int base = (row * AP + q * 32) >> 1;
                if (row < nv) {
                    int s = es[row];
                    const float4* src4 = (const float4*)(hfout + (size_t)s * HD + q * 32);
#pragma unroll
                    for (int i = 0; i < 8; i++) {
                        float4 v = src4[i];
                        Au[base + i * 2]     = f2bf(v.x) | ((unsigned int)f2bf(v.y) << 16);
                        Au[base + i * 2 + 1] = f2bf(v.z) | ((unsigned int)f2bf(v.w) << 16);
                    }
                } else {
#pragma unroll
                    for (int i = 0; i < 16; i++) Au[base + i] = 0u;
                }
            }
            // metadata via shfl (lanes 0..15 hold rows rbase..rbase+15)
            int sg = 0, sd = 0;
            if (ln < 16) {
                int row = rbase + ln;
                if (row < nv) { sg = p.gate[es[row]]; sd = ed[row]; }
            }

            const unsigned short* WB = p.wbmlp + (size_t)gi * 3 * 16384;
            float b1v[8], b2v[8], b3v[8];
#pragma unroll
            for (int nt = 0; nt < 8; nt++) {
                b1v[nt] = p.b1[gi * HD + nt * 16 + lc];
                b2v[nt] = p.b2[gi * HD + nt * 16 + lc];
                b3v[nt] = p.b3[gi * HD + nt * 16 + lc];
            }

            // layer 1: relu(hsW1[gate_src] + hf@W1bot + b1), in-place
            {
                bf16x8 af[4];
#pragma unroll
                for (int kc = 0; kc < 4; kc++)
                    af[kc] = *(bf16x8*)&A[(rbase + lc) * AP + kc * 32 + quad * 8];
                for (int nt = 0; nt < 8; nt++) {
                    f32x4 acc = {0.f, 0.f, 0.f, 0.f};
#pragma unroll
                    for (int kc = 0; kc < 4; kc++) {
                        bf16x8 bf = *(const bf16x8*)&WB[((nt * 4 + kc) * 64 + ln) * 8];
                        acc = __builtin_amdgcn_mfma_f32_16x16x32_bf16(af[kc], bf, acc, 0, 0, 0);
                    }
#pragma unroll
                    for (int r = 0; r < 4; r++) {
                        int row = rbase + quad * 4 + r;
                        int sgr = __shfl(sg, quad * 4 + r);
                        float v = acc[r] + hsw[(gi * 6 + sgr) * 132 + nt * 16 + lc] + b1v[nt];
                        A[row * AP + nt * 16 + lc] = f2bf(fmaxf(v, 0.f));
                    }
                }
            }
            // layer 2
            {
                bf16x8 af[4];
#pragma unroll
                for (int kc = 0; kc < 4; kc++)
                    af[kc] = *(bf16x8*)&A[(rbase + lc) * AP + kc * 32 + quad * 8];
                for (int nt = 0; nt < 8; nt++) {
                    f32x4 acc = {0.f, 0.f, 0.f, 0.f};
#pragma unroll
                    for (int kc = 0; kc < 4; kc++) {
                        bf16x8 bf = *(const bf16x8*)&WB[16384 + ((nt * 4 + kc) * 64 + ln) * 8];
                        acc = __builtin_amdgcn_mfma_f32_16x16x32_bf16(af[kc], bf, acc, 0, 0, 0);
                    }
#pragma unroll
                    for (int r = 0; r < 4; r++) {
                        int row = rbase + quad * 4 + r;
                        A[row * AP + nt * 16 + lc] = f2bf(fmaxf(acc[r] + b2v[nt], 0.f));
                    }
                }
            }
            // layer 3 + scatter-add
            {
                bf16x8 af[4];
#pragma unroll
                for (int kc = 0; kc < 4; kc++)
                    af[kc] = *(bf16x8*)&A[(rbase + lc) * AP + kc * 32 + quad * 8];
                for (int nt = 0; nt < 8; nt++) {
                    f32x4 acc = {0.f, 0.f, 0.f, 0.f};
#pragma unroll
                    for (int kc = 0; kc < 4; kc++) {
                        bf16x8 bf = *(const bf16x8*)&WB[2 * 16384 + ((nt * 4 + kc) * 64 + ln) * 8];
                        acc = __builtin_amdgcn_mfma_f32_16x16x32_bf16(af[kc], bf, acc, 0, 0, 0);
                    }
#pragma unroll
                    for (int r = 0; r < 4; r++) {
                        int row = rbase + quad * 4 + r;
                        if (row < nv) {
                            int sdr = __shfl(sd, quad * 4 + r);
                            atomicAdd(&p.msg[((size_t)(gi * CAPN) + sdr) * HD + nt * 16 + lc],
                                      acc[r] + b3v[nt]);
                        }
                    }
                }
            }
        }

        __threadfence();
        grid.sync();

        // ---- gru phase: hf = (1-z)*tanh(i_n + r*bhN), h_old == 0 ----
        for (int t = bid; t < 192; t += NBLK) {
            int gi = t % 3;
            int tile = (t / 3) * 64;
            int glob = (l - 1) * 3 + gi;
            int cnt = p.ncnt[glob]; if (cnt > CAPN) cnt = CAPN;
            if (tile >= cnt) continue;
            int nv = min(64, cnt - tile);

            // wave-local staging of msg rows (bf16) + re-zero (msg invariant)
            {
                int row = rbase + (ln >> 2), q = ln & 3;
                float4* msg4 = (float4*)(p.msg + ((size_t)(gi * CAPN + tile + row)) * HD + q * 32);
                unsigned int* Mu = (unsigned int*)A;
                int base = (row * AP + q * 32) >> 1;
#pragma unroll
                for (int i = 0; i < 8; i++) {
                    float4 v = msg4[i];
                    Mu[base + i * 2]     = f2bf(v.x) | ((unsigned int)f2bf(v.y) << 16);
                    Mu[base + i * 2 + 1] = f2bf(v.z) | ((unsigned int)f2bf(v.w) << 16);
                    msg4[i] = make_float4(0.f, 0.f, 0.f, 0.f);
                }
            }
            int nd = -1;
            if (ln < 16) {
                int row = rbase + ln;
                nd = (row < nv) ? p.nlist[glob * CAPN + tile + row] : -1;
            }

            const unsigned short* WB = p.wbih + (size_t)gi * 49152;
            bf16x8 af[4];
#pragma unroll
            for (int kc = 0; kc < 4; kc++)
                af[kc] = *(bf16x8*)&A[(rbase + lc) * AP + kc * 32 + quad * 8];

            for (int nt = 0; nt < 8; nt++) {
                f32x4 aR = {0.f, 0.f, 0.f, 0.f};
                f32x4 aZ = {0.f, 0.f, 0.f, 0.f};
                f32x4 aN = {0.f, 0.f, 0.f, 0.f};
#pragma unroll
                for (int kc = 0; kc < 4; kc++) {
                    bf16x8 bR = *(const bf16x8*)&WB[(((nt)      * 4 + kc) * 64 + ln) * 8];
                    bf16x8 bZ = *(const bf16x8*)&WB[(((nt + 8)  * 4 + kc) * 64 + ln) * 8];
                    bf16x8 bN = *(const bf16x8*)&WB[(((nt + 16) * 4 + kc) * 64 + ln) * 8];
                    aR = __builtin_amdgcn_mfma_f32_16x16x32_bf16(af[kc], bR, aR, 0, 0, 0);
                    aZ = __builtin_amdgcn_mfma_f32_16x16x32_bf16(af[kc], bZ, aZ, 0, 0, 0);
                    aN = __builtin_amdgcn_mfma_f32_16x16x32_bf16(af[kc], bN, aN, 0, 0, 0);
                }
                int c = nt * 16 + lc;
                float biR = p.bih[gi * 384 + c],       bhR = p.bhh[gi * 384 + c];
                float biZ = p.bih[gi * 384 + 128 + c], bhZ = p.bhh[gi * 384 + 128 + c];
                float biN = p.bih[gi * 384 + 256 + c], bhN = p.bhh[gi * 384 + 256 + c];
#pragma unroll
                for (int r = 0; r < 4; r++) {
                    int row = rbase + quad * 4 + r;
                    int n = __shfl(nd, quad * 4 + r);
                    if (n >= 0 && row < nv) {
                        float ir = aR[r] + biR + bhR;
                        float iz = aZ[r] + biZ + bhZ;
                        float inn = aN[r] + biN;
                        float rg = 1.f / (1.f + expf(-ir));
                        float zg = 1.f / (1.f + expf(-iz));
                        float nst = tanhf(inn + rg * bhN);
                        hfout[(size_t)n * HD + c] = (1.f - zg) * nst;
                    }
                }
            }
        }

        __threadfence();
        grid.sync();
    }
}

extern "C" void kernel_launch(void* const* d_in, const int* in_sizes, int n_in,
                              void* d_out, int out_size, void* d_ws, size_t ws_size,
                              hipStream_t stream) {
    char* ws = (char*)d_ws;

    Params p;
    p.gate = (const int*)d_in[0];
    p.lvl  = (const int*)d_in[1];
    p.ei   = (const int*)d_in[2];
    p.Ws   = (const float*)d_in[3];
    p.Wt   = (const float*)d_in[4];
    p.hs_W = (const float*)d_in[5];
    p.hs_b = (const float*)d_in[6];
    p.w1 = (const float*)d_in[7];
    p.b1 = (const float*)d_in[8];
    p.w2 = (const float*)d_in[9];
    p.b2 = (const float*)d_in[10];
    p.w3 = (const float*)d_in[11];
    p.b3 = (const float*)d_in[12];
    p.wih = (const float*)d_in[13];
    // d_in[14] = gru_whh: unused (h_old provably zero for every updated node)
    p.bih = (const float*)d_in[15];
    p.bhh = (const float*)d_in[16];
    p.out = (float*)d_out;
    p.ncnt    = (int*)(ws + OFF_NCNT);
    p.ecnt    = (int*)(ws + OFF_ECNT);
    p.hs_type = (float*)(ws + OFF_HSTYPE);
    p.hsW1    = (float*)(ws + OFF_HSW1);
    p.wbmlp   = (unsigned short*)(ws + OFF_WBMLP);
    p.wbih    = (unsigned short*)(ws + OFF_WBIH);
    p.nlist   = (int*)(ws + OFF_NLIST);
    p.nslot   = (int*)(ws + OFF_NSLOT);
    p.esrc    = (int*)(ws + OFF_ESRC);
    p.edsl    = (int*)(ws + OFF_EDSL);
    p.msg     = (float*)(ws + OFF_MSG);

    // zero only what must be zero: group counters + msg accumulator
    hipMemsetAsync(ws + OFF_NCNT, 0, 512, stream);
    hipMemsetAsync(ws + OFF_MSG, 0, MSG_BYTES, stream);

    void* kp[] = {&p};
    hipLaunchCooperativeKernel((void*)fused_kernel, dim3(NBLK), dim3(NTHR),
                               kp, 0, stream);
}

// Round 5
// 403.876 us; speedup vs baseline: 3.0520x; 3.0520x over previous
//
#include <hip/hip_runtime.h>
#include <math.h>

#define NN 100000
#define NE 200000
#define HD 128
#define CAPN 4096
#define CAPE 8192
#define NGROUP 21
#define AP 136   // bf16 LDS row pitch (shorts)
#define NTHR 256

typedef short bf16x8 __attribute__((ext_vector_type(8)));
typedef float f32x4 __attribute__((ext_vector_type(4)));

// workspace byte offsets
#define OFF_NCNT   0                // 21 ints
#define OFF_ECNT   256              // 21 ints (LIVE edge counts)
#define OFF_ZCNT   512              // 21*4096*8 ints (zero-edge counts per dst,src-gate)
#define MEMSET_BYTES 2753024        // covers ncnt+ecnt+zcnt
#define OFF_HSTYPE 2753024          // 6*128 f32
#define OFF_HSW1   2756096          // 3*6*128 f32
#define OFF_ZTAB   2765312          // 3*6*128 f32 (msg of a zero-hf src, per gi,src-gate)
#define OFF_WBMLP  2774528          // 3*3*16384 bf16 swizzled B-frags
#define OFF_WBIH   3069440          // 3*49152 bf16 swizzled B-frags
#define OFF_NLIST  3364352          // 21*4096 ints
#define OFF_NSLOT  3708416          // NN ints
#define OFF_ESRC   4108416          // 21*8192 ints (live only)
#define OFF_EDSL   4796544          // 21*8192 ints
#define OFF_MSG    5484672          // 21*4096*128 f32 (per-level msg buffers)

#define SWTOT (3 * 3 * 16384 + 3 * 49152)

__device__ __forceinline__ int gi_of(int g) {
    return (g == 3) ? 0 : (g == 2) ? 1 : (g == 5) ? 2 : -1;
}

__device__ __forceinline__ unsigned short f2bf(float f) {
    unsigned int u = __float_as_uint(f);
    u += 0x7FFF + ((u >> 16) & 1);   // RNE
    return (unsigned short)(u >> 16);
}

// ---------------------------------------------------------------------------
// prep1: block 0 -> hs_type + hsW1; blocks 1..18 -> ztab rows (self-contained);
// blocks 19+ -> weight swizzle + group_nodes (LDS-aggregated).
// ---------------------------------------------------------------------------
__global__ __launch_bounds__(NTHR) void prep1_kernel(
    const int* __restrict__ gate, const int* __restrict__ lvl,
    const float* __restrict__ Ws, const float* __restrict__ Wt,
    const float* __restrict__ hs_W, const float* __restrict__ hs_b,
    const float* __restrict__ w1, const float* __restrict__ b1,
    const float* __restrict__ w2, const float* __restrict__ b2,
    const float* __restrict__ w3, const float* __restrict__ b3,
    const float* __restrict__ wih,
    float* __restrict__ hs_type, float* __restrict__ hsW1,
    float* __restrict__ ztab,
    unsigned short* __restrict__ wbmlp, unsigned short* __restrict__ wbih,
    int* __restrict__ ncnt, int* __restrict__ nlist, int* __restrict__ nslot) {
    __shared__ float lht[6 * HD];
    __shared__ float s0[HD], s1[HD], s2[HD];
    __shared__ int lcnt[NGROUP], lbase[NGROUP];
    const int bid = blockIdx.x, tid = threadIdx.x;

    if (bid == 0) {
        for (int idx = tid; idx < 6 * HD; idx += NTHR) {
            int t = idx >> 7, c = idx & 127;
            float acc = hs_b[c];
            for (int k = 0; k < HD; k++) acc = fmaf(Ws[t * HD + k], hs_W[k * HD + c], acc);
            for (int k = 0; k < HD; k++) acc = fmaf(Wt[t * HD + k], hs_W[(HD + k) * HD + c], acc);
            lht[idx] = acc;
            hs_type[idx] = acc;
        }
        __syncthreads();
        for (int idx = tid; idx < 3 * 6 * HD; idx += NTHR) {
            int gi = idx / (6 * HD);
            int t = (idx >> 7) % 6;
            int c = idx & 127;
            const float* w = w1 + gi * (2 * HD * HD);  // top half rows 0..127
            float acc = 0.f;
            for (int k = 0; k < HD; k++) acc = fmaf(lht[t * HD + k], w[k * HD + c], acc);
            hsW1[idx] = acc;
        }
    } else if (bid <= 18) {
        // ztab[gi][t] = MLP_gi([hs_type[t], 0]) — fp32, self-contained
        int gi = (bid - 1) / 6, t = (bid - 1) % 6;
        int c = tid;
        if (c < HD) {
            float acc = hs_b[c];
            for (int k = 0; k < HD; k++) acc = fmaf(Ws[t * HD + k], hs_W[k * HD + c], acc);
            for (int k = 0; k < HD; k++) acc = fmaf(Wt[t * HD + k], hs_W[(HD + k) * HD + c], acc);
            s0[c] = acc;
        }
        __syncthreads();
        if (c < HD) {
            const float* w = w1 + gi * (2 * HD * HD);  // top half
            float acc = b1[gi * HD + c];
            for (int k = 0; k < HD; k++) acc = fmaf(s0[k], w[k * HD + c], acc);
            s1[c] = fmaxf(acc, 0.f);
        }
        __syncthreads();
        if (c < HD) {
            const float* w = w2 + gi * (HD * HD);
            float acc = b2[gi * HD + c];
            for (int k = 0; k < HD; k++) acc = fmaf(s1[k], w[k * HD + c], acc);
            s2[c] = fmaxf(acc, 0.f);
        }
        __syncthreads();
        if (c < HD) {
            const float* w = w3 + gi * (HD * HD);
            float acc = b3[gi * HD + c];
            for (int k = 0; k < HD; k++) acc = fmaf(s2[k], w[k * HD + c], acc);
            ztab[(gi * 6 + t) * HD + c] = acc;
        }
    } else {
        const int nb = gridDim.x - 19;          // worker blocks
        const int wb = bid - 19;
        // weight swizzle into MFMA B-fragment layout
        for (int id = wb * NTHR + tid; id < SWTOT; id += nb * NTHR) {
            if (id < 3 * 3 * 16384) {
                int gi = id / 49152;
                int rem = id % 49152;
                int layer = rem / 16384;
                int e = rem % 16384;
                int k = e >> 7, n = e & 127;
                float v;
                if (layer == 0)      v = w1[gi * (2 * HD * HD) + (HD + k) * HD + n];
                else if (layer == 1) v = w2[gi * (HD * HD) + k * HD + n];
                else                 v = w3[gi * (HD * HD) + k * HD + n];
                int nt = n >> 4, kc = k >> 5, kq = (k >> 3) & 3, j = k & 7;
                int L = (kq << 4) | (n & 15);
                wbmlp[(size_t)(gi * 3 + layer) * 16384 + ((nt * 4 + kc) * 64 + L) * 8 + j] = f2bf(v);
            } else {
                int id2 = id - 3 * 3 * 16384;
                int gi = id2 / 49152;
                int e = id2 % 49152;
                int k = e / 384, n = e % 384;             // B[k][n] = wih[n][k]
                float v = wih[gi * (384 * HD) + n * HD + k];
                int nt = n >> 4, kc = k >> 5, kq = (k >> 3) & 3, j = k & 7;
                int L = (kq << 4) | (n & 15);
                wbih[(size_t)gi * 49152 + ((nt * 4 + kc) * 64 + L) * 8 + j] = f2bf(v);
            }
        }
        // group_nodes (LDS-aggregated)
        for (int base = wb * NTHR; base < NN; base += nb * NTHR) {
            if (tid < NGROUP) lcnt[tid] = 0;
            __syncthreads();
            int i = base + tid;
            int glob = -1, local = 0;
            if (i < NN) {
                int gi = gi_of(gate[i]);
                int l = lvl[i];
                if (gi >= 0 && l >= 1) {
                    glob = (l - 1) * 3 + gi;
                    local = atomicAdd(&lcnt[glob], 1);
                }
            }
            __syncthreads();
            if (tid < NGROUP) {
                int cc = lcnt[tid];
                lbase[tid] = cc ? atomicAdd(&ncnt[tid], cc) : 0;
            }
            __syncthreads();
            if (glob >= 0) {
                int slot = lbase[glob] + local;
                if (slot < CAPN) {
                    nlist[glob * CAPN + slot] = i;
                    nslot[i] = slot;
                }
            }
            __syncthreads();
        }
    }
}

// ---------------------------------------------------------------------------
// prep2: scatter hs / zero hf + group_edges with live/zero classification.
// Zero-hf edges become one int atomicAdd into zcnt[(glob,dslot,src_gate)].
// ---------------------------------------------------------------------------
__global__ __launch_bounds__(NTHR) void prep2_kernel(
    const int* __restrict__ gate, const int* __restrict__ lvl,
    const int* __restrict__ ei, const int* __restrict__ nslot,
    const float* __restrict__ hs_type, float* __restrict__ out,
    int* __restrict__ ecnt, int* __restrict__ esrc, int* __restrict__ edsl,
    int* __restrict__ zcnt) {
    __shared__ int lcnt[NGROUP], lbase[NGROUP];
    const int bid = blockIdx.x, tid = threadIdx.x;
    const int stride = gridDim.x * NTHR;

    const float4* ht4 = (const float4*)hs_type;
    float4* o4 = (float4*)out;
    for (int idx = bid * NTHR + tid; idx < NN * 32; idx += stride) {
        int i = idx >> 5, q = idx & 31;
        o4[idx] = ht4[gate[i] * 32 + q];
        o4[(size_t)NN * 32 + idx] = make_float4(0.f, 0.f, 0.f, 0.f);
    }

    for (int base = 0; base < NE; base += stride) {
        if (tid < NGROUP) lcnt[tid] = 0;
        __syncthreads();
        int e = base + bid * NTHR + tid;
        int glob = -1, local = 0, s = 0, dsl = 0;
        if (e < NE) {
            int d = ei[NE + e];
            int gd = gi_of(gate[d]);
            int ld = lvl[d];
            if (gd >= 0 && ld >= 1) {
                int g = (ld - 1) * 3 + gd;
                s = ei[e];
                dsl = nslot[d];
                int gs = gate[s], ls = lvl[s];
                bool live = (gi_of(gs) >= 0) && (ls >= 1) && (ls < ld);
                if (live) {
                    glob = g;
                    local = atomicAdd(&lcnt[glob], 1);
                } else {
                    // zero-hf src: message is ztab[gd][gs] — just count it
                    atomicAdd(&zcnt[((size_t)g * CAPN + dsl) * 8 + gs], 1);
                }
            }
        }
        __syncthreads();
        if (tid < NGROUP) {
            int cc = lcnt[tid];
            lbase[tid] = cc ? atomicAdd(&ecnt[tid], cc) : 0;
        }
        __syncthreads();
        if (glob >= 0) {
            int slot = lbase[glob] + local;
            if (slot < CAPE) {
                esrc[glob * CAPE + slot] = s;
                edsl[glob * CAPE + slot] = dsl;
            }
        }
        __syncthreads();
    }
}

// ---------------------------------------------------------------------------
// prep3: initialize per-level msg buffers = Sum_t zcnt[t] * ztab[gi][t]
// (zero-hf edge contributions for ALL levels, folded once).
// ---------------------------------------------------------------------------
__global__ __launch_bounds__(NTHR) void prep3_kernel(
    const int* __restrict__ ncnt, const int* __restrict__ zcnt,
    const float* __restrict__ ztab, float* __restrict__ msg) {
    const int stride = gridDim.x * NTHR;
    const f32x4* zt4 = (const f32x4*)ztab;
    f32x4* m4 = (f32x4*)msg;
    for (int id = blockIdx.x * NTHR + threadIdx.x; id < NGROUP * CAPN * 32; id += stride) {
        int row = id >> 5, lane = id & 31;
        int glob = row >> 12;           // /CAPN
        int slot = row & (CAPN - 1);
        int cnt = ncnt[glob]; if (cnt > CAPN) cnt = CAPN;
        if (slot >= cnt) continue;
        int gi = glob % 3;
        const int* zc = zcnt + (size_t)row * 8;
        f32x4 acc = {0.f, 0.f, 0.f, 0.f};
#pragma unroll
        for (int t = 0; t < 6; t++) {
            int ct = zc[t];
            if (ct) {
                float f = (float)ct;
                f32x4 z = zt4[(gi * 6 + t) * 32 + lane];
                acc.x = fmaf(f, z.x, acc.x);
                acc.y = fmaf(f, z.y, acc.y);
                acc.z = fmaf(f, z.z, acc.z);
                acc.w = fmaf(f, z.w, acc.w);
            }
        }
        m4[(size_t)row * 32 + lane] = acc;
    }
}

// ---------------------------------------------------------------------------
// msg_kernel: 3-layer MFMA MLP over LIVE edges only + atomic scatter-add.
// 64 edges/block, wave-local bands, one __syncthreads (hsw staging).
// grid = 3 x 128.
// ---------------------------------------------------------------------------
__global__ __launch_bounds__(NTHR) void msg_kernel(
    int level, const int* __restrict__ gate, const float* __restrict__ hf,
    const unsigned short* __restrict__ wbmlp,
    const float* __restrict__ b1, const float* __restrict__ b2,
    const float* __restrict__ b3, const float* __restrict__ hsW1,
    const int* __restrict__ ecnt, const int* __restrict__ esrc,
    const int* __restrict__ edsl, float* __restrict__ msg) {
    int gi = blockIdx.x >> 7;
    int tile = (blockIdx.x & 127) * 64;
    int glob = (level - 1) * 3 + gi;
    int cnt = ecnt[glob]; if (cnt > CAPE) cnt = CAPE;
    if (tile >= cnt) return;
    int nv = min(64, cnt - tile);

    __shared__ unsigned short A[64 * AP];
    __shared__ float hsw[6 * 132];

    int tid = threadIdx.x;
    const int ln = tid & 63, wv = tid >> 6;
    const int lc = ln & 15, quad = ln >> 4;
    const int rbase = wv * 16;
    const int* es = esrc + glob * CAPE + tile;
    const int* ed = edsl + glob * CAPE + tile;
    float* msgL = msg + (size_t)glob * CAPN * HD;

    for (int i = tid; i < 6 * 132; i += NTHR) {
        int t = i / 132, c = i % 132;
        hsw[i] = (c < HD) ? hsW1[(gi * 6 + t) * HD + c] : 0.f;
    }
    // wave-local staging of hf[src] (bf16)
    {
        int row = rbase + (ln >> 2), q = ln & 3;
        unsigned int* Au = (unsigned int*)A;
        int base = (row * AP + q * 32) >> 1;
        if (row < nv) {
            int s = es[row];
            const float4* src4 = (const float4*)(hf + (size_t)s * HD + q * 32);
#pragma unroll
            for (int i = 0; i < 8; i++) {
                float4 v = src4[i];
                Au[base + i * 2]     = f2bf(v.x) | ((unsigned int)f2bf(v.y) << 16);
                Au[base + i * 2 + 1] = f2bf(v.z) | ((unsigned int)f2bf(v.w) << 16);
            }
        } else {
#pragma unroll
            for (int i = 0; i < 16; i++) Au[base + i] = 0u;
        }
    }
    int sg = 0, sd = 0;
    if (ln < 16) {
        int row = rbase + ln;
        if (row < nv) { sg = gate[es[row]]; sd = ed[row]; }
    }
    __syncthreads();

    const unsigned short* WB = wbmlp + (size_t)gi * 3 * 16384;
    float b1v[8], b2v[8], b3v[8];
#pragma unroll
    for (int nt = 0; nt < 8; nt++) {
        b1v[nt] = b1[gi * HD + nt * 16 + lc];
        b2v[nt] = b2[gi * HD + nt * 16 + lc];
        b3v[nt] = b3[gi * HD + nt * 16 + lc];
    }

    // layer 1: relu(hsW1[gate_src] + hf@W1bot + b1), in-place
    {
        bf16x8 af[4];
#pragma unroll
        for (int kc = 0; kc < 4; kc++)
            af[kc] = *(bf16x8*)&A[(rbase + lc) * AP + kc * 32 + quad * 8];
        for (int nt = 0; nt < 8; nt++) {
            f32x4 acc = {0.f, 0.f, 0.f, 0.f};
#pragma unroll
            for (int kc = 0; kc < 4; kc++) {
                bf16x8 bf = *(const bf16x8*)&WB[((nt * 4 + kc) * 64 + ln) * 8];
                acc = __builtin_amdgcn_mfma_f32_16x16x32_bf16(af[kc], bf, acc, 0, 0, 0);
            }
#pragma unroll
            for (int r = 0; r < 4; r++) {
                int row = rbase + quad * 4 + r;
                int sgr = __shfl(sg, quad * 4 + r);
                float v = acc[r] + hsw[sgr * 132 + nt * 16 + lc] + b1v[nt];
                A[row * AP + nt * 16 + lc] = f2bf(fmaxf(v, 0.f));
            }
        }
    }
    // layer 2
    {
        bf16x8 af[4];
#pragma unroll
        for (int kc = 0; kc < 4; kc++)
            af[kc] = *(bf16x8*)&A[(rbase + lc) * AP + kc * 32 + quad * 8];
        for (int nt = 0; nt < 8; nt++) {
            f32x4 acc = {0.f, 0.f, 0.f, 0.f};
#pragma unroll
            for (int kc = 0; kc < 4; kc++) {
                bf16x8 bf = *(const bf16x8*)&WB[16384 + ((nt * 4 + kc) * 64 + ln) * 8];
                acc = __builtin_amdgcn_mfma_f32_16x16x32_bf16(af[kc], bf, acc, 0, 0, 0);
            }
#pragma unroll
            for (int r = 0; r < 4; r++) {
                int row = rbase + quad * 4 + r;
                A[row * AP + nt * 16 + lc] = f2bf(fmaxf(acc[r] + b2v[nt], 0.f));
            }
        }
    }
    // layer 3 + scatter-add
    {
        bf16x8 af[4];
#pragma unroll
        for (int kc = 0; kc < 4; kc++)
            af[kc] = *(bf16x8*)&A[(rbase + lc) * AP + kc * 32 + quad * 8];
        for (int nt = 0; nt < 8; nt++) {
            f32x4 acc = {0.f, 0.f, 0.f, 0.f};
#pragma unroll
            for (int kc = 0; kc < 4; kc++) {
                bf16x8 bf = *(const bf16x8*)&WB[2 * 16384 + ((nt * 4 + kc) * 64 + ln) * 8];
                acc = __builtin_amdgcn_mfma_f32_16x16x32_bf16(af[kc], bf, acc, 0, 0, 0);
            }
#pragma unroll
            for (int r = 0; r < 4; r++) {
                int row = rbase + quad * 4 + r;
                if (row < nv) {
                    int sdr = __shfl(sd, quad * 4 + r);
                    atomicAdd(&msgL[(size_t)sdr * HD + nt * 16 + lc], acc[r] + b3v[nt]);
                }
            }
        }
    }
}

// ---------------------------------------------------------------------------
// gru_kernel: gin = msg @ wih.T + bih ; gh = bhh (h_old == 0).
// Reads per-level msg buffer (no re-zero). grid = 3 x 64.
// ---------------------------------------------------------------------------
__global__ __launch_bounds__(NTHR) void gru_kernel(
    int level, const int* __restrict__ ncnt, const int* __restrict__ nlist,
    const unsigned short* __restrict__ wbih, const float* __restrict__ bih,
    const float* __restrict__ bhh, const float* __restrict__ msg,
    float* __restrict__ out) {
    int gi = blockIdx.x >> 6;
    int tile = (blockIdx.x & 63) * 64;
    int glob = (level - 1) * 3 + gi;
    int cnt = ncnt[glob]; if (cnt > CAPN) cnt = CAPN;
    if (tile >= cnt) return;
    int nv = min(64, cnt - tile);

    __shared__ unsigned short M[64 * AP];
    int tid = threadIdx.x;
    const int ln = tid & 63, wv = tid >> 6;
    const int lc = ln & 15, quad = ln >> 4;
    const int rbase = wv * 16;
    const float* msgL = msg + (size_t)glob * CAPN * HD;

    {
        int row = rbase + (ln >> 2), q = ln & 3;
        const float4* msg4 = (const float4*)(msgL + (size_t)(tile + row) * HD + q * 32);
        unsigned int* Mu = (unsigned int*)M;
        int base = (row * AP + q * 32) >> 1;
#pragma unroll
        for (int i = 0; i < 8; i++) {
            float4 v = msg4[i];
            Mu[base + i * 2]     = f2bf(v.x) | ((unsigned int)f2bf(v.y) << 16);
            Mu[base + i * 2 + 1] = f2bf(v.z) | ((unsigned int)f2bf(v.w) << 16);
        }
    }
    int nd = -1;
    if (ln < 16) {
        int row = rbase + ln;
        nd = (row < nv) ? nlist[glob * CAPN + tile + row] : -1;
    }

    const unsigned short* WB = wbih + (size_t)gi * 49152;
    bf16x8 af[4];
#pragma unroll
    for (int kc = 0; kc < 4; kc++)
        af[kc] = *(bf16x8*)&M[(rbase + lc) * AP + kc * 32 + quad * 8];

    float* hfout = out + (size_t)NN * HD;
    for (int nt = 0; nt < 8; nt++) {
        f32x4 aR = {0.f, 0.f, 0.f, 0.f};
        f32x4 aZ = {0.f, 0.f, 0.f, 0.f};
        f32x4 aN = {0.f, 0.f, 0.f, 0.f};
#pragma unroll
        for (int kc = 0; kc < 4; kc++) {
            bf16x8 bR = *(const bf16x8*)&WB[(((nt)      * 4 + kc) * 64 + ln) * 8];
            bf16x8 bZ = *(const bf16x8*)&WB[(((nt + 8)  * 4 + kc) * 64 + ln) * 8];
            bf16x8 bN = *(const bf16x8*)&WB[(((nt + 16) * 4 + kc) * 64 + ln) * 8];
            aR = __builtin_amdgcn_mfma_f32_16x16x32_bf16(af[kc], bR, aR, 0, 0, 0);
            aZ = __builtin_amdgcn_mfma_f32_16x16x32_bf16(af[kc], bZ, aZ, 0, 0, 0);
            aN = __builtin_amdgcn_mfma_f32_16x16x32_bf16(af[kc], bN, aN, 0, 0, 0);
        }
        int c = nt * 16 + lc;
        float biR = bih[gi * 384 + c],       bhR = bhh[gi * 384 + c];
        float biZ = bih[gi * 384 + 128 + c], bhZ = bhh[gi * 384 + 128 + c];
        float biN = bih[gi * 384 + 256 + c], bhN = bhh[gi * 384 + 256 + c];
#pragma unroll
        for (int r = 0; r < 4; r++) {
            int row = rbase + quad * 4 + r;
            int n = __shfl(nd, quad * 4 + r);
            if (n >= 0 && row < nv) {
                float ir = aR[r] + biR + bhR;
                float iz = aZ[r] + biZ + bhZ;
                float inn = aN[r] + biN;
                float rg = 1.f / (1.f + expf(-ir));
                float zg = 1.f / (1.f + expf(-iz));
                float nst = tanhf(inn + rg * bhN);
                hfout[(size_t)n * HD + c] = (1.f - zg) * nst;
            }
        }
    }
}

extern "C" void kernel_launch(void* const* d_in, const int* in_sizes, int n_in,
                              void* d_out, int out_size, void* d_ws, size_t ws_size,
                              hipStream_t stream) {
    const int* gate = (const int*)d_in[0];
    const int* lvl  = (const int*)d_in[1];
    const int* ei   = (const int*)d_in[2];
    const float* Ws   = (const float*)d_in[3];
    const float* Wt   = (const float*)d_in[4];
    const float* hs_W = (const float*)d_in[5];
    const float* hs_b = (const float*)d_in[6];
    const float* w1 = (const float*)d_in[7];
    const float* b1 = (const float*)d_in[8];
    const float* w2 = (const float*)d_in[9];
    const float* b2 = (const float*)d_in[10];
    const float* w3 = (const float*)d_in[11];
    const float* b3 = (const float*)d_in[12];
    const float* wih = (const float*)d_in[13];
    // d_in[14] = gru_whh: unused (h_old provably zero for every updated node)
    const float* bih = (const float*)d_in[15];
    const float* bhh = (const float*)d_in[16];
    float* out = (float*)d_out;
    char* ws = (char*)d_ws;

    int*   ncnt    = (int*)(ws + OFF_NCNT);
    int*   ecnt    = (int*)(ws + OFF_ECNT);
    int*   zcnt    = (int*)(ws + OFF_ZCNT);
    float* hs_type = (float*)(ws + OFF_HSTYPE);
    float* hsW1    = (float*)(ws + OFF_HSW1);
    float* ztab    = (float*)(ws + OFF_ZTAB);
    unsigned short* wbmlp = (unsigned short*)(ws + OFF_WBMLP);
    unsigned short* wbih  = (unsigned short*)(ws + OFF_WBIH);
    int*   nlist   = (int*)(ws + OFF_NLIST);
    int*   nslot   = (int*)(ws + OFF_NSLOT);
    int*   esrc    = (int*)(ws + OFF_ESRC);
    int*   edsl    = (int*)(ws + OFF_EDSL);
    float* msg     = (float*)(ws + OFF_MSG);

    hipMemsetAsync(ws, 0, MEMSET_BYTES, stream);

    prep1_kernel<<<256, NTHR, 0, stream>>>(gate, lvl, Ws, Wt, hs_W, hs_b,
                                           w1, b1, w2, b2, w3, b3, wih,
                                           hs_type, hsW1, ztab, wbmlp, wbih,
                                           ncnt, nlist, nslot);
    prep2_kernel<<<1024, NTHR, 0, stream>>>(gate, lvl, ei, nslot, hs_type, out,
                                            ecnt, esrc, edsl, zcnt);
    prep3_kernel<<<1344, NTHR, 0, stream>>>(ncnt, zcnt, ztab, msg);

    const float* hf = out + (size_t)NN * HD;
    for (int l = 1; l < 8; l++) {
        if (l > 1)  // level 1 provably has zero live edges
            msg_kernel<<<3 * 128, NTHR, 0, stream>>>(l, gate, hf, wbmlp, b1, b2, b3,
                                                     hsW1, ecnt, esrc, edsl, msg);
        gru_kernel<<<3 * 64, NTHR, 0, stream>>>(l, ncnt, nlist, wbih, bih, bhh, msg, out);
    }
}